// Round 9
// baseline (365.741 us; speedup 1.0000x reference)
//
#include <hip/hip_runtime.h>
#include <hip/hip_bf16.h>

typedef short short8 __attribute__((ext_vector_type(8)));
typedef float floatx4 __attribute__((ext_vector_type(4)));

#define B_  256
#define T_  512
#define D_  64
#define L_  32
#define H_  128
#define PXS 516   // packed pre_x row stride (floats): [t][col*4+e], ~0 conflicts (R4/R5-verified)
#define HRS 136   // h_ring row stride in shorts: row bank offset 4 (R7-verified)

__device__ inline short f2bf(float f) {
    __hip_bfloat16 h = __float2bfloat16(f);
    union { __hip_bfloat16 h; short s; } u;
    u.h = h;
    return u.s;
}

// lgkm-only barrier: LDS ordering without draining vmcnt — global prefetches
// stay in flight across steps.
__device__ inline void block_sync_lds() {
    asm volatile("s_waitcnt lgkmcnt(0)\n\ts_barrier" ::: "memory");
}

// Gate pre-activations are computed PRE-SCALED by the exp2 argument factor:
// i,f,o rows of Whh/Wih/S scaled by -log2(e); g rows by -2*log2(e). EW is then
// sigmoid(x) = rcp(1+exp2(gi_scaled)), tanh = 2*rcp(1+exp2(gg_scaled))-1 —
// no v_mul on the dependent chain (the MFMA does the scaling for free).
#define SCL1 (-1.4426950408889634f)   // -log2(e)
#define SCL2 (-2.8853900817779268f)   // -2*log2(e)

// One block per batch element; 512 threads = 8 waves; 1 block/CU.
// R8 skeleton (lgkm barriers, staggered duties) + serial-chain cuts:
//   tw==2 : stage x_(W+1) regs->x_lds + issue global prefetch x_(W+2)
//   tw==4 : wave-0 out-dot for window W-1 via MFMA (padded ring)
//   tw==14: load x A-frags from x_lds into persistent regs
//   tw==15: window MFMA for W+1 + packed pre_x dump (wave-local)
//   px for step t+1 read into a register BEFORE the barrier (pre_x wave-local)
__global__ __launch_bounds__(512, 2) void tamlstm_kernel(
    const float* __restrict__ xd,    // [B,T,D]
    const float* __restrict__ xs,    // [B,L]
    const float* __restrict__ Wih,   // [4H,D]
    const float* __restrict__ Whh,   // [4H,H]
    const float* __restrict__ Wzh,   // [4H,L]
    const float* __restrict__ bias,  // [4H]
    const float* __restrict__ Wout,  // [1,H]
    const float* __restrict__ bout,  // [1]
    float* __restrict__ out)         // [B,T]
{
    const int b    = blockIdx.x;
    const int tid  = threadIdx.x;
    const int w    = tid >> 6;    // wave 0..7
    const int lane = tid & 63;
    const int l15  = lane & 15;
    const int q    = lane >> 4;   // quad 0..3

    __shared__ __align__(16) float pre_x[16][PXS];   // 33 KB, wave-local r/w
    __shared__ __align__(16) short x_lds[16][72];    // 2.25 KB staged x window
    __shared__ __align__(16) short h_ring[32 * HRS]; // 8.5 KB padded bf16 ring
    __shared__ __align__(16) float out_lds[T_];      // 2 KB output buffer

    // zero ring row 0 only (h_{-1}); rows 1..31 written before read
    if (tid < 64) ((int*)h_ring)[tid] = 0;

    const int col = (w << 4) + l15;                 // hidden column 0..127

    // per-gate exp2-argument scale (i,f,o: -log2e; g: -2log2e)
    const float SC[4] = {SCL1, SCL1, SCL2, SCL1};

    // ---- B-fragments (bf16, PRE-SCALED) in registers ----
    // B-frag element j = SC[e] * W[gate = col + 128e][k = 32s + 8q + j]
    short8 whh[4][4];  // [gate e][k-chunk s], K=128
    short8 wih[4][2];  // [e][s], K=64
    #pragma unroll
    for (int e = 0; e < 4; ++e) {
        const int g = col + (e << 7);
        const float sc = SC[e];
        const float* rh = Whh + g * H_;
        #pragma unroll
        for (int s = 0; s < 4; ++s) {
            const float* p = rh + s * 32 + q * 8;
            short8 v;
            #pragma unroll
            for (int j = 0; j < 8; ++j) v[j] = f2bf(p[j] * sc);
            whh[e][s] = v;
        }
        const float* ri = Wih + g * D_;
        #pragma unroll
        for (int s = 0; s < 2; ++s) {
            const float* p = ri + s * 32 + q * 8;
            short8 v;
            #pragma unroll
            for (int j = 0; j < 8; ++j) v[j] = f2bf(p[j] * sc);
            wih[e][s] = v;
        }
    }
    // W_out B-frag (broadcast over N; UNSCALED — consumes h)
    short8 wof[4];
    #pragma unroll
    for (int s = 0; s < 4; ++s) {
        short8 v;
        #pragma unroll
        for (int j = 0; j < 8; ++j) v[j] = f2bf(Wout[s * 32 + q * 8 + j]);
        wof[s] = v;
    }
    const float bo = bout[0];

    // ---- static part: SC[e] * (bias + x_static @ Wzh^T) ----
    float S[4];
    const float* xsb = xs + b * L_;
    #pragma unroll
    for (int e = 0; e < 4; ++e) {
        const int g = col + (e << 7);
        const float* wz = Wzh + g * L_;
        float a = bias[g];
        for (int l = 0; l < L_; ++l) a += xsb[l] * wz[l];
        S[e] = a * SC[e];
    }

    const float* xb = xd + (size_t)b * T_ * D_;
    const floatx4 ZERO = {0.f, 0.f, 0.f, 0.f};

    // ---- prologue: window-0 pre_x direct from global; load x_1 into regs ----
    {
        const float* xr = xb + l15 * D_;            // timestep row l15
        float4 u0 = *(const float4*)(xr + q * 8);
        float4 u1 = *(const float4*)(xr + q * 8 + 4);
        float4 u2 = *(const float4*)(xr + 32 + q * 8);
        float4 u3 = *(const float4*)(xr + 32 + q * 8 + 4);
        short8 a0, a1;
        a0[0]=f2bf(u0.x); a0[1]=f2bf(u0.y); a0[2]=f2bf(u0.z); a0[3]=f2bf(u0.w);
        a0[4]=f2bf(u1.x); a0[5]=f2bf(u1.y); a0[6]=f2bf(u1.z); a0[7]=f2bf(u1.w);
        a1[0]=f2bf(u2.x); a1[1]=f2bf(u2.y); a1[2]=f2bf(u2.z); a1[3]=f2bf(u2.w);
        a1[4]=f2bf(u3.x); a1[5]=f2bf(u3.y); a1[6]=f2bf(u3.z); a1[7]=f2bf(u3.w);
        floatx4 aw[4];
        #pragma unroll
        for (int e = 0; e < 4; ++e) {
            aw[e] = __builtin_amdgcn_mfma_f32_16x16x32_bf16(a0, wih[e][0], ZERO, 0, 0, 0);
            aw[e] = __builtin_amdgcn_mfma_f32_16x16x32_bf16(a1, wih[e][1], aw[e], 0, 0, 0);
        }
        #pragma unroll
        for (int r = 0; r < 4; ++r) {
            floatx4 pk = {aw[0][r] + S[0], aw[1][r] + S[1],
                          aw[2][r] + S[2], aw[3][r] + S[3]};
            *(floatx4*)&pre_x[q * 4 + r][col << 2] = pk;
        }
    }
    float xr0, xr1;
    {   // x of window 1 into regs (staged at tw==2 of window 0)
        float2 x2 = ((const float2*)(xb + 16 * D_))[tid];
        xr0 = x2.x; xr1 = x2.y;
    }
    // px for t=0 (wave-local read of own dump)
    floatx4 px = *(const floatx4*)&pre_x[0][col << 2];

    float c = 0.0f;
    short8 afx0 = {}, afx1 = {};   // persistent x A-frags for the window MFMA
    __syncthreads();   // ring row 0 visible (one-time vmcnt drain, harmless)

    for (int t = 0; t < T_; ++t) {
        const int tw = t & 15;

        // ---- h A-frag reads (the only post-barrier LDS dependency) ----
        const short8* hp = (const short8*)&h_ring[(t & 31) * HRS];
        short8 af0 = hp[q];
        short8 af1 = hp[4 + q];
        short8 af2 = hp[8 + q];
        short8 af3 = hp[12 + q];

        // ---- 4 independent 4-deep MFMA chains ----
        floatx4 acc[4];
        #pragma unroll
        for (int e = 0; e < 4; ++e)
            acc[e] = __builtin_amdgcn_mfma_f32_16x16x32_bf16(af0, whh[e][0], ZERO, 0, 0, 0);
        #pragma unroll
        for (int e = 0; e < 4; ++e)
            acc[e] = __builtin_amdgcn_mfma_f32_16x16x32_bf16(af1, whh[e][1], acc[e], 0, 0, 0);
        #pragma unroll
        for (int e = 0; e < 4; ++e)
            acc[e] = __builtin_amdgcn_mfma_f32_16x16x32_bf16(af2, whh[e][2], acc[e], 0, 0, 0);
        #pragma unroll
        for (int e = 0; e < 4; ++e)
            acc[e] = __builtin_amdgcn_mfma_f32_16x16x32_bf16(af3, whh[e][3], acc[e], 0, 0, 0);

        // ---- duty: stage x_(W+1) to x_lds + prefetch x_(W+2) (tw==2) ----
        if (tw == 2) {
            if (t + 14 < T_) {      // window W+1 exists
                unsigned pk = (unsigned)(unsigned short)f2bf(xr0) |
                              ((unsigned)(unsigned short)f2bf(xr1) << 16);
                const int e2 = tid * 2;
                *(unsigned*)&x_lds[e2 >> 6][e2 & 63] = pk;
            }
            if (t + 30 < T_) {      // window W+2 exists; 16-step flight
                float2 x2 = ((const float2*)(xb + (t + 30) * D_))[tid];
                xr0 = x2.x; xr1 = x2.y;
            }
        }

        // ---- duty: wave-0 out-dot for window W-1 via MFMA (tw==4) ----
        if (tw == 4 && t >= 20 && w == 0) {
            const int tp = (t & ~15) - 16;
            const short* ap = &h_ring[((tp + l15 + 1) & 31) * HRS];
            floatx4 d0 = __builtin_amdgcn_mfma_f32_16x16x32_bf16(
                             *(const short8*)(ap + q * 8),      wof[0], ZERO, 0, 0, 0);
            floatx4 d1 = __builtin_amdgcn_mfma_f32_16x16x32_bf16(
                             *(const short8*)(ap + 32 + q * 8), wof[1], ZERO, 0, 0, 0);
            floatx4 d2 = __builtin_amdgcn_mfma_f32_16x16x32_bf16(
                             *(const short8*)(ap + 64 + q * 8), wof[2], ZERO, 0, 0, 0);
            floatx4 d3 = __builtin_amdgcn_mfma_f32_16x16x32_bf16(
                             *(const short8*)(ap + 96 + q * 8), wof[3], ZERO, 0, 0, 0);
            floatx4 od = (d0 + d1) + (d2 + d3);
            if (l15 == 0) {
                floatx4 ov = {od[0] + bo, od[1] + bo, od[2] + bo, od[3] + bo};
                *(floatx4*)&out_lds[tp + q * 4] = ov;
            }
        }

        // ---- duty: preload x A-frags for window MFMA (tw==14) ----
        if (tw == 14 && t + 2 < T_) {
            afx0 = *(const short8*)&x_lds[l15][q * 8];
            afx1 = *(const short8*)&x_lds[l15][32 + q * 8];
        }

        // ---- elementwise: pre-scaled gates -> exp2 directly ----
        const float gi = acc[0].x + px[0];
        const float gf = acc[1].x + px[1];
        const float gg = acc[2].x + px[2];
        const float go = acc[3].x + px[3];
        const float is = __builtin_amdgcn_rcpf(1.0f + __builtin_amdgcn_exp2f(gi));
        const float fs = __builtin_amdgcn_rcpf(1.0f + __builtin_amdgcn_exp2f(gf));
        const float os = __builtin_amdgcn_rcpf(1.0f + __builtin_amdgcn_exp2f(go));
        const float tg = 2.0f * __builtin_amdgcn_rcpf(1.0f + __builtin_amdgcn_exp2f(gg)) - 1.0f;
        c = fs * c + is * tg;
        const float th = 2.0f * __builtin_amdgcn_rcpf(
                             1.0f + __builtin_amdgcn_exp2f(SCL2 * c)) - 1.0f;
        const float h = os * th;

        if (lane < 16) h_ring[((t + 1) & 31) * HRS + col] = f2bf(h);

        // ---- duty: window-(W+1) x@Wih MFMA + packed dump (tw==15) ----
        if (tw == 15 && t + 1 < T_) {
            floatx4 aw[4];
            #pragma unroll
            for (int e = 0; e < 4; ++e) {
                aw[e] = __builtin_amdgcn_mfma_f32_16x16x32_bf16(afx0, wih[e][0], ZERO, 0, 0, 0);
                aw[e] = __builtin_amdgcn_mfma_f32_16x16x32_bf16(afx1, wih[e][1], aw[e], 0, 0, 0);
            }
            #pragma unroll
            for (int r = 0; r < 4; ++r) {
                floatx4 pk = {aw[0][r] + S[0], aw[1][r] + S[1],
                              aw[2][r] + S[2], aw[3][r] + S[3]};
                *(floatx4*)&pre_x[q * 4 + r][col << 2] = pk;
            }
        }

        // ---- px for step t+1, read BEFORE the barrier (pre_x wave-local;
        //      in-order DS completion makes this safe after the dump) ----
        px = *(const floatx4*)&pre_x[(t + 1) & 15][col << 2];

        block_sync_lds();
    }

    // ---- epilogue: out-dot for final window (t' = 496..511), store out ----
    if (w == 0) {
        const int tp = T_ - 16;
        const short* ap = &h_ring[((tp + l15 + 1) & 31) * HRS];
        floatx4 d0 = __builtin_amdgcn_mfma_f32_16x16x32_bf16(
                         *(const short8*)(ap + q * 8),      wof[0], ZERO, 0, 0, 0);
        floatx4 d1 = __builtin_amdgcn_mfma_f32_16x16x32_bf16(
                         *(const short8*)(ap + 32 + q * 8), wof[1], ZERO, 0, 0, 0);
        floatx4 d2 = __builtin_amdgcn_mfma_f32_16x16x32_bf16(
                         *(const short8*)(ap + 64 + q * 8), wof[2], ZERO, 0, 0, 0);
        floatx4 d3 = __builtin_amdgcn_mfma_f32_16x16x32_bf16(
                         *(const short8*)(ap + 96 + q * 8), wof[3], ZERO, 0, 0, 0);
        floatx4 od = (d0 + d1) + (d2 + d3);
        if (l15 == 0) {
            floatx4 ov = {od[0] + bo, od[1] + bo, od[2] + bo, od[3] + bo};
            *(floatx4*)&out_lds[tp + q * 4] = ov;
        }
    }
    __syncthreads();
    out[b * T_ + tid] = out_lds[tid];
}

extern "C" void kernel_launch(void* const* d_in, const int* in_sizes, int n_in,
                              void* d_out, int out_size, void* d_ws, size_t ws_size,
                              hipStream_t stream) {
    const float* xd   = (const float*)d_in[0];
    const float* xs   = (const float*)d_in[1];
    const float* Wih  = (const float*)d_in[2];
    const float* Whh  = (const float*)d_in[3];
    const float* Wzh  = (const float*)d_in[4];
    const float* bias = (const float*)d_in[5];
    const float* Wout = (const float*)d_in[6];
    const float* bout = (const float*)d_in[7];
    float* o = (float*)d_out;
    hipLaunchKernelGGL(tamlstm_kernel, dim3(B_), dim3(512), 0, stream,
                       xd, xs, Wih, Whh, Wzh, bias, Wout, bout, o);
}

// Round 10
// 347.254 us; speedup vs baseline: 1.0532x; 1.0532x over previous
//
#include <hip/hip_runtime.h>
#include <hip/hip_bf16.h>

typedef short short8 __attribute__((ext_vector_type(8)));
typedef float floatx4 __attribute__((ext_vector_type(4)));

#define B_  256
#define T_  512
#define D_  64
#define L_  32
#define H_  128
#define PXS 516   // packed pre_x row stride (floats): [t][col*4+e], ~0 conflicts (R4/R5-verified)
#define HRS 136   // h_ring row stride in shorts: row bank offset 4 (R7-verified)

__device__ inline short f2bf(float f) {
    __hip_bfloat16 h = __float2bfloat16(f);
    union { __hip_bfloat16 h; short s; } u;
    u.h = h;
    return u.s;
}

__device__ inline float fast_sigmoid(float x) {
    return __builtin_amdgcn_rcpf(1.0f + __expf(-x));
}

__device__ inline float fast_tanh(float x) {
    float e = __expf(-2.0f * x);
    return 2.0f * __builtin_amdgcn_rcpf(1.0f + e) - 1.0f;
}

// lgkm-only barrier: orders LDS without draining vmcnt — the tw==0 global
// prefetch stays in flight across all 16 intervening barriers (compiler
// inserts its own vmcnt wait at the consume point, 16 steps later).
__device__ inline void block_sync_lds() {
    asm volatile("s_waitcnt lgkmcnt(0)\n\ts_barrier" ::: "memory");
}

// One block per batch element; 512 threads = 8 waves; 1 block/CU.
// R7 structure (best: 292.6us) unchanged except in-loop barriers are
// lgkm-only. All window duties execute at STEP TOP (post-barrier) where they
// overlap the MFMA pipe — R8/R9 showed pre-barrier placement costs 1:1 on the
// serial chain. Wave w owns hidden cols [16w,16w+16) x 4 gates -> i/f/g/o of
// a column in one lane's accumulators -> in-register EW; c in registers.
__global__ __launch_bounds__(512, 2) void tamlstm_kernel(
    const float* __restrict__ xd,    // [B,T,D]
    const float* __restrict__ xs,    // [B,L]
    const float* __restrict__ Wih,   // [4H,D]
    const float* __restrict__ Whh,   // [4H,H]
    const float* __restrict__ Wzh,   // [4H,L]
    const float* __restrict__ bias,  // [4H]
    const float* __restrict__ Wout,  // [1,H]
    const float* __restrict__ bout,  // [1]
    float* __restrict__ out)         // [B,T]
{
    const int b    = blockIdx.x;
    const int tid  = threadIdx.x;
    const int w    = tid >> 6;    // wave 0..7
    const int lane = tid & 63;
    const int l15  = lane & 15;
    const int q    = lane >> 4;   // quad 0..3

    __shared__ __align__(16) float pre_x[16][PXS];   // 33 KB, wave-local r/w
    __shared__ __align__(16) short x_lds[16][72];    // 2.25 KB staged x window
    __shared__ __align__(16) short h_ring[32 * HRS]; // 8.5 KB padded bf16 ring
    __shared__ __align__(16) float out_lds[T_];      // 2 KB output buffer

    // zero ring row 0 only (h_{-1}); rows 1..31 are written before read
    if (tid < 64) ((int*)h_ring)[tid] = 0;

    const int col = (w << 4) + l15;                 // hidden column 0..127

    // ---- B-fragments (bf16) in registers ----
    // B-frag element j = W[gate = col + 128e][k = 32s + 8q + j]
    short8 whh[4][4];  // [gate e][k-chunk s], K=128
    short8 wih[4][2];  // [e][s], K=64
    #pragma unroll
    for (int e = 0; e < 4; ++e) {
        const int g = col + (e << 7);
        const float* rh = Whh + g * H_;
        #pragma unroll
        for (int s = 0; s < 4; ++s) {
            const float* p = rh + s * 32 + q * 8;
            short8 v;
            #pragma unroll
            for (int j = 0; j < 8; ++j) v[j] = f2bf(p[j]);
            whh[e][s] = v;
        }
        const float* ri = Wih + g * D_;
        #pragma unroll
        for (int s = 0; s < 2; ++s) {
            const float* p = ri + s * 32 + q * 8;
            short8 v;
            #pragma unroll
            for (int j = 0; j < 8; ++j) v[j] = f2bf(p[j]);
            wih[e][s] = v;
        }
    }
    // W_out B-frag (broadcast over N: element j = wout[32s+8q+j])
    short8 wof[4];
    #pragma unroll
    for (int s = 0; s < 4; ++s) {
        short8 v;
        #pragma unroll
        for (int j = 0; j < 8; ++j) v[j] = f2bf(Wout[s * 32 + q * 8 + j]);
        wof[s] = v;
    }
    const float bo = bout[0];

    // ---- static part: bias + x_static @ Wzh^T (folded into pre_x at dump) ----
    float S[4];
    const float* xsb = xs + b * L_;
    #pragma unroll
    for (int e = 0; e < 4; ++e) {
        const int g = col + (e << 7);
        const float* wz = Wzh + g * L_;
        float a = bias[g];
        for (int l = 0; l < L_; ++l) a += xsb[l] * wz[l];
        S[e] = a;
    }

    const float* xb = xd + (size_t)b * T_ * D_;
    const floatx4 ZERO = {0.f, 0.f, 0.f, 0.f};      // hoisted acc init

    // ---- prologue: stage window 0, compute its pre_x, prefetch window 1 ----
    float xr0, xr1;
    {
        float2 x2 = ((const float2*)xb)[tid];
        unsigned pk = (unsigned)(unsigned short)f2bf(x2.x) |
                      ((unsigned)(unsigned short)f2bf(x2.y) << 16);
        const int e2 = tid * 2;
        *(unsigned*)&x_lds[e2 >> 6][e2 & 63] = pk;
    }
    __syncthreads();   // x_lds + ring row 0 visible (one-time full drain)
    {
        float2 x2 = ((const float2*)(xb + 16 * D_))[tid];   // window 1 prefetch
        xr0 = x2.x; xr1 = x2.y;
    }
    {
        floatx4 aw[4];
        #pragma unroll
        for (int s = 0; s < 2; ++s) {
            short8 af = *(const short8*)&x_lds[l15][s * 32 + q * 8];
            #pragma unroll
            for (int e = 0; e < 4; ++e)
                aw[e] = __builtin_amdgcn_mfma_f32_16x16x32_bf16(af, wih[e][s],
                            s == 0 ? ZERO : aw[e], 0, 0, 0);
        }
        #pragma unroll
        for (int r = 0; r < 4; ++r) {
            floatx4 pk = {aw[0][r] + S[0], aw[1][r] + S[1],
                          aw[2][r] + S[2], aw[3][r] + S[3]};
            *(floatx4*)&pre_x[q * 4 + r][col << 2] = pk;
        }
    }

    float c = 0.0f;

    for (int t = 0; t < T_; ++t) {
        const int tw = t & 15;

        if (tw == 0 && t > 0) {
            // ---- wave-0: deferred out-dot for window W-1 via MFMA ----
            if (w == 0) {
                const int tp = t - 16;
                const short* ap = &h_ring[((tp + l15 + 1) & 31) * HRS];
                floatx4 d0 = __builtin_amdgcn_mfma_f32_16x16x32_bf16(
                                 *(const short8*)(ap + q * 8),      wof[0], ZERO, 0, 0, 0);
                floatx4 d1 = __builtin_amdgcn_mfma_f32_16x16x32_bf16(
                                 *(const short8*)(ap + 32 + q * 8), wof[1], ZERO, 0, 0, 0);
                floatx4 d2 = __builtin_amdgcn_mfma_f32_16x16x32_bf16(
                                 *(const short8*)(ap + 64 + q * 8), wof[2], ZERO, 0, 0, 0);
                floatx4 d3 = __builtin_amdgcn_mfma_f32_16x16x32_bf16(
                                 *(const short8*)(ap + 96 + q * 8), wof[3], ZERO, 0, 0, 0);
                floatx4 od = (d0 + d1) + (d2 + d3);
                if (l15 == 0) {
                    floatx4 ov = {od[0] + bo, od[1] + bo, od[2] + bo, od[3] + bo};
                    *(floatx4*)&out_lds[tp + q * 4] = ov;
                }
            }

            // ---- stage x window W (regs prefetched 16 steps ago; compiler
            //      inserts the vmcnt wait here, 16 steps after issue) ----
            {
                unsigned pk = (unsigned)(unsigned short)f2bf(xr0) |
                              ((unsigned)(unsigned short)f2bf(xr1) << 16);
                const int e2 = tid * 2;
                *(unsigned*)&x_lds[e2 >> 6][e2 & 63] = pk;
            }
            block_sync_lds();  // x_lds visible; orders out-dot ring reads

            // prefetch window W+1 (16-step flight; lgkm barriers don't drain)
            if (t + 16 < T_) {
                float2 x2 = ((const float2*)(xb + (t + 16) * D_))[tid];
                xr0 = x2.x; xr1 = x2.y;
            }

            // ---- window MFMA (M=16 timesteps) + packed dump (wave-local) ----
            floatx4 aw[4];
            #pragma unroll
            for (int s = 0; s < 2; ++s) {
                short8 af = *(const short8*)&x_lds[l15][s * 32 + q * 8];
                #pragma unroll
                for (int e = 0; e < 4; ++e)
                    aw[e] = __builtin_amdgcn_mfma_f32_16x16x32_bf16(af, wih[e][s],
                                s == 0 ? ZERO : aw[e], 0, 0, 0);
            }
            #pragma unroll
            for (int r = 0; r < 4; ++r) {
                floatx4 pk = {aw[0][r] + S[0], aw[1][r] + S[1],
                              aw[2][r] + S[2], aw[3][r] + S[3]};
                *(floatx4*)&pre_x[q * 4 + r][col << 2] = pk;
            }
        }

        // ---- recurrent MFMA: g += h_{t-1} @ Whh^T (4 chains of 4) ----
        const short8* hp = (const short8*)&h_ring[(t & 31) * HRS];
        short8 af0 = hp[q];
        short8 af1 = hp[4 + q];
        short8 af2 = hp[8 + q];
        short8 af3 = hp[12 + q];
        floatx4 px = *(const floatx4*)&pre_x[tw][col << 2];

        floatx4 acc[4];
        #pragma unroll
        for (int e = 0; e < 4; ++e)
            acc[e] = __builtin_amdgcn_mfma_f32_16x16x32_bf16(af0, whh[e][0], ZERO, 0, 0, 0);
        #pragma unroll
        for (int e = 0; e < 4; ++e)
            acc[e] = __builtin_amdgcn_mfma_f32_16x16x32_bf16(af1, whh[e][1], acc[e], 0, 0, 0);
        #pragma unroll
        for (int e = 0; e < 4; ++e)
            acc[e] = __builtin_amdgcn_mfma_f32_16x16x32_bf16(af2, whh[e][2], acc[e], 0, 0, 0);
        #pragma unroll
        for (int e = 0; e < 4; ++e)
            acc[e] = __builtin_amdgcn_mfma_f32_16x16x32_bf16(af3, whh[e][3], acc[e], 0, 0, 0);

        // ---- elementwise (quads duplicate; S/bias already in px) ----
        const float gi = acc[0].x + px[0];
        const float gf = acc[1].x + px[1];
        const float gg = acc[2].x + px[2];
        const float go = acc[3].x + px[3];
        const float is = fast_sigmoid(gi);
        const float fs = fast_sigmoid(gf);
        const float os = fast_sigmoid(go);
        const float tg = fast_tanh(gg);
        c = fs * c + is * tg;
        const float h = os * fast_tanh(c);

        if (lane < 16) h_ring[((t + 1) & 31) * HRS + col] = f2bf(h);

        block_sync_lds();
    }

    // ---- epilogue: out-dot for final window (t' = 496..511), store out ----
    if (w == 0) {
        const int tp = T_ - 16;
        const short* ap = &h_ring[((tp + l15 + 1) & 31) * HRS];
        floatx4 d0 = __builtin_amdgcn_mfma_f32_16x16x32_bf16(
                         *(const short8*)(ap + q * 8),      wof[0], ZERO, 0, 0, 0);
        floatx4 d1 = __builtin_amdgcn_mfma_f32_16x16x32_bf16(
                         *(const short8*)(ap + 32 + q * 8), wof[1], ZERO, 0, 0, 0);
        floatx4 d2 = __builtin_amdgcn_mfma_f32_16x16x32_bf16(
                         *(const short8*)(ap + 64 + q * 8), wof[2], ZERO, 0, 0, 0);
        floatx4 d3 = __builtin_amdgcn_mfma_f32_16x16x32_bf16(
                         *(const short8*)(ap + 96 + q * 8), wof[3], ZERO, 0, 0, 0);
        floatx4 od = (d0 + d1) + (d2 + d3);
        if (l15 == 0) {
            floatx4 ov = {od[0] + bo, od[1] + bo, od[2] + bo, od[3] + bo};
            *(floatx4*)&out_lds[tp + q * 4] = ov;
        }
    }
    __syncthreads();
    out[b * T_ + tid] = out_lds[tid];
}

extern "C" void kernel_launch(void* const* d_in, const int* in_sizes, int n_in,
                              void* d_out, int out_size, void* d_ws, size_t ws_size,
                              hipStream_t stream) {
    const float* xd   = (const float*)d_in[0];
    const float* xs   = (const float*)d_in[1];
    const float* Wih  = (const float*)d_in[2];
    const float* Whh  = (const float*)d_in[3];
    const float* Wzh  = (const float*)d_in[4];
    const float* bias = (const float*)d_in[5];
    const float* Wout = (const float*)d_in[6];
    const float* bout = (const float*)d_in[7];
    float* o = (float*)d_out;
    hipLaunchKernelGGL(tamlstm_kernel, dim3(B_), dim3(512), 0, stream,
                       xd, xs, Wih, Whh, Wzh, bias, Wout, bout, o);
}

// Round 11
// 339.199 us; speedup vs baseline: 1.0782x; 1.0237x over previous
//
#include <hip/hip_runtime.h>
#include <hip/hip_bf16.h>

typedef short short8 __attribute__((ext_vector_type(8)));
typedef float floatx4 __attribute__((ext_vector_type(4)));

#define B_  256
#define T_  512
#define D_  64
#define L_  32
#define H_  128
#define PXS 516   // packed pre_x row stride (floats): [t][col*4+e], 0 conflicts (R4/R5-verified)
#define HRS 136   // h_ring row stride in shorts: 136*2B=272B -> row bank offset 4, conflict-free

__device__ inline short f2bf(float f) {
    __hip_bfloat16 h = __float2bfloat16(f);
    union { __hip_bfloat16 h; short s; } u;
    u.h = h;
    return u.s;
}

__device__ inline float fast_sigmoid(float x) {
    return __builtin_amdgcn_rcpf(1.0f + __expf(-x));
}

__device__ inline float fast_tanh(float x) {
    float e = __expf(-2.0f * x);
    return 2.0f * __builtin_amdgcn_rcpf(1.0f + e) - 1.0f;
}

// One block per batch element; 512 threads = 8 waves; 1 block/CU.
// BEST VARIANT (R7, 292.6us; verified best across R2-R10 ablations).
// Wave w owns hidden cols [16w,16w+16) x 4 gates -> i/f/g/o of a column in one
// lane's accumulators -> in-register EW; cell state c in registers.
// Window step (tw==0): wave-0 out-dot for window W-1 via MFMA (padded ring),
// stage x, barrier, prefetch next x, window MFMA, packed pre_x dump
// (wave-local single buffer). Per step: 4 chained-MFMA gate accumulators, one
// b128 px read, EW, h -> padded ring, __syncthreads.
// Ablation record: per-step branch ladders, staggered duties, lgkm-only
// barriers, pre-barrier duty placement, unpadded MFMA ring reads, same-step
// global consume ALL regressed. Latency-bound on the serial recurrent chain
// (~1372 cyc/step vs 620 cyc MFMA-pipe floor); fp8-MX fails the 8e-3
// threshold; cross-CU N-split loses to exchange latency.
__global__ __launch_bounds__(512, 2) void tamlstm_kernel(
    const float* __restrict__ xd,    // [B,T,D]
    const float* __restrict__ xs,    // [B,L]
    const float* __restrict__ Wih,   // [4H,D]
    const float* __restrict__ Whh,   // [4H,H]
    const float* __restrict__ Wzh,   // [4H,L]
    const float* __restrict__ bias,  // [4H]
    const float* __restrict__ Wout,  // [1,H]
    const float* __restrict__ bout,  // [1]
    float* __restrict__ out)         // [B,T]
{
    const int b    = blockIdx.x;
    const int tid  = threadIdx.x;
    const int w    = tid >> 6;    // wave 0..7
    const int lane = tid & 63;
    const int l15  = lane & 15;
    const int q    = lane >> 4;   // quad 0..3

    __shared__ __align__(16) float pre_x[16][PXS];   // 33 KB, wave-local r/w
    __shared__ __align__(16) short x_lds[16][72];    // 2.25 KB staged x window
    __shared__ __align__(16) short h_ring[32 * HRS]; // 8.5 KB padded bf16 ring
    __shared__ __align__(16) float out_lds[T_];      // 2 KB output buffer

    // zero ring row 0 only (h_{-1}); rows 1..31 are written before read
    if (tid < 64) ((int*)h_ring)[tid] = 0;

    const int col = (w << 4) + l15;                 // hidden column 0..127

    // ---- B-fragments (bf16) in registers ----
    // B-frag element j = W[gate = col + 128e][k = 32s + 8q + j]
    short8 whh[4][4];  // [gate e][k-chunk s], K=128
    short8 wih[4][2];  // [e][s], K=64
    #pragma unroll
    for (int e = 0; e < 4; ++e) {
        const int g = col + (e << 7);
        const float* rh = Whh + g * H_;
        #pragma unroll
        for (int s = 0; s < 4; ++s) {
            const float* p = rh + s * 32 + q * 8;
            short8 v;
            #pragma unroll
            for (int j = 0; j < 8; ++j) v[j] = f2bf(p[j]);
            whh[e][s] = v;
        }
        const float* ri = Wih + g * D_;
        #pragma unroll
        for (int s = 0; s < 2; ++s) {
            const float* p = ri + s * 32 + q * 8;
            short8 v;
            #pragma unroll
            for (int j = 0; j < 8; ++j) v[j] = f2bf(p[j]);
            wih[e][s] = v;
        }
    }
    // W_out B-frag (broadcast over N: element j = wout[32s+8q+j])
    short8 wof[4];
    #pragma unroll
    for (int s = 0; s < 4; ++s) {
        short8 v;
        #pragma unroll
        for (int j = 0; j < 8; ++j) v[j] = f2bf(Wout[s * 32 + q * 8 + j]);
        wof[s] = v;
    }
    const float bo = bout[0];

    // ---- static part: bias + x_static @ Wzh^T (folded into pre_x at dump) ----
    float S[4];
    const float* xsb = xs + b * L_;
    #pragma unroll
    for (int e = 0; e < 4; ++e) {
        const int g = col + (e << 7);
        const float* wz = Wzh + g * L_;
        float a = bias[g];
        for (int l = 0; l < L_; ++l) a += xsb[l] * wz[l];
        S[e] = a;
    }

    const float* xb = xd + (size_t)b * T_ * D_;
    const floatx4 ZERO = {0.f, 0.f, 0.f, 0.f};      // hoisted acc init

    // ---- prologue: stage window 0, compute its pre_x, prefetch window 1 ----
    float xr0, xr1;
    {
        float2 x2 = ((const float2*)xb)[tid];
        unsigned pk = (unsigned)(unsigned short)f2bf(x2.x) |
                      ((unsigned)(unsigned short)f2bf(x2.y) << 16);
        const int e2 = tid * 2;
        *(unsigned*)&x_lds[e2 >> 6][e2 & 63] = pk;
    }
    __syncthreads();   // x_lds + ring row 0 visible
    {
        float2 x2 = ((const float2*)(xb + 16 * D_))[tid];   // window 1 prefetch
        xr0 = x2.x; xr1 = x2.y;
    }
    {
        floatx4 aw[4];
        #pragma unroll
        for (int s = 0; s < 2; ++s) {
            short8 af = *(const short8*)&x_lds[l15][s * 32 + q * 8];
            #pragma unroll
            for (int e = 0; e < 4; ++e)
                aw[e] = __builtin_amdgcn_mfma_f32_16x16x32_bf16(af, wih[e][s],
                            s == 0 ? ZERO : aw[e], 0, 0, 0);
        }
        #pragma unroll
        for (int r = 0; r < 4; ++r) {
            floatx4 pk = {aw[0][r] + S[0], aw[1][r] + S[1],
                          aw[2][r] + S[2], aw[3][r] + S[3]};
            *(floatx4*)&pre_x[q * 4 + r][col << 2] = pk;
        }
    }

    float c = 0.0f;

    for (int t = 0; t < T_; ++t) {
        const int tw = t & 15;

        if (tw == 0 && t > 0) {
            // ---- wave-0: deferred out-dot for window W-1 via MFMA ----
            if (w == 0) {
                const int tp = t - 16;
                const short* ap = &h_ring[((tp + l15 + 1) & 31) * HRS];
                floatx4 d0 = __builtin_amdgcn_mfma_f32_16x16x32_bf16(
                                 *(const short8*)(ap + q * 8),      wof[0], ZERO, 0, 0, 0);
                floatx4 d1 = __builtin_amdgcn_mfma_f32_16x16x32_bf16(
                                 *(const short8*)(ap + 32 + q * 8), wof[1], ZERO, 0, 0, 0);
                floatx4 d2 = __builtin_amdgcn_mfma_f32_16x16x32_bf16(
                                 *(const short8*)(ap + 64 + q * 8), wof[2], ZERO, 0, 0, 0);
                floatx4 d3 = __builtin_amdgcn_mfma_f32_16x16x32_bf16(
                                 *(const short8*)(ap + 96 + q * 8), wof[3], ZERO, 0, 0, 0);
                floatx4 od = (d0 + d1) + (d2 + d3);
                if (l15 == 0) {
                    floatx4 ov = {od[0] + bo, od[1] + bo, od[2] + bo, od[3] + bo};
                    *(floatx4*)&out_lds[tp + q * 4] = ov;
                }
            }

            // ---- stage x window W (regs prefetched 16 steps ago) ----
            {
                unsigned pk = (unsigned)(unsigned short)f2bf(xr0) |
                              ((unsigned)(unsigned short)f2bf(xr1) << 16);
                const int e2 = tid * 2;
                *(unsigned*)&x_lds[e2 >> 6][e2 & 63] = pk;
            }
            __syncthreads();  // x_lds visible (also orders out-dot ring reads)

            // prefetch window W+1 while MFMAs run
            if (t + 16 < T_) {
                float2 x2 = ((const float2*)(xb + (t + 16) * D_))[tid];
                xr0 = x2.x; xr1 = x2.y;
            }

            // ---- window MFMA (M=16 timesteps) + packed dump (wave-local) ----
            floatx4 aw[4];
            #pragma unroll
            for (int s = 0; s < 2; ++s) {
                short8 af = *(const short8*)&x_lds[l15][s * 32 + q * 8];
                #pragma unroll
                for (int e = 0; e < 4; ++e)
                    aw[e] = __builtin_amdgcn_mfma_f32_16x16x32_bf16(af, wih[e][s],
                                s == 0 ? ZERO : aw[e], 0, 0, 0);
            }
            #pragma unroll
            for (int r = 0; r < 4; ++r) {
                floatx4 pk = {aw[0][r] + S[0], aw[1][r] + S[1],
                              aw[2][r] + S[2], aw[3][r] + S[3]};
                *(floatx4*)&pre_x[q * 4 + r][col << 2] = pk;
            }
        }

        // ---- recurrent MFMA: g += h_{t-1} @ Whh^T (4 indep 4-deep chains) ----
        const short8* hp = (const short8*)&h_ring[(t & 31) * HRS];
        short8 af0 = hp[q];
        short8 af1 = hp[4 + q];
        short8 af2 = hp[8 + q];
        short8 af3 = hp[12 + q];
        floatx4 px = *(const floatx4*)&pre_x[tw][col << 2];

        floatx4 acc[4];
        #pragma unroll
        for (int e = 0; e < 4; ++e)
            acc[e] = __builtin_amdgcn_mfma_f32_16x16x32_bf16(af0, whh[e][0], ZERO, 0, 0, 0);
        #pragma unroll
        for (int e = 0; e < 4; ++e)
            acc[e] = __builtin_amdgcn_mfma_f32_16x16x32_bf16(af1, whh[e][1], acc[e], 0, 0, 0);
        #pragma unroll
        for (int e = 0; e < 4; ++e)
            acc[e] = __builtin_amdgcn_mfma_f32_16x16x32_bf16(af2, whh[e][2], acc[e], 0, 0, 0);
        #pragma unroll
        for (int e = 0; e < 4; ++e)
            acc[e] = __builtin_amdgcn_mfma_f32_16x16x32_bf16(af3, whh[e][3], acc[e], 0, 0, 0);

        // ---- elementwise (quads duplicate; S/bias already in px) ----
        const float gi = acc[0].x + px[0];
        const float gf = acc[1].x + px[1];
        const float gg = acc[2].x + px[2];
        const float go = acc[3].x + px[3];
        const float is = fast_sigmoid(gi);
        const float fs = fast_sigmoid(gf);
        const float os = fast_sigmoid(go);
        const float tg = fast_tanh(gg);
        c = fs * c + is * tg;
        const float h = os * fast_tanh(c);

        if (lane < 16) h_ring[((t + 1) & 31) * HRS + col] = f2bf(h);

        __syncthreads();
    }

    // ---- epilogue: out-dot for final window (t' = 496..511), store out ----
    if (w == 0) {
        const int tp = T_ - 16;
        const short* ap = &h_ring[((tp + l15 + 1) & 31) * HRS];
        floatx4 d0 = __builtin_amdgcn_mfma_f32_16x16x32_bf16(
                         *(const short8*)(ap + q * 8),      wof[0], ZERO, 0, 0, 0);
        floatx4 d1 = __builtin_amdgcn_mfma_f32_16x16x32_bf16(
                         *(const short8*)(ap + 32 + q * 8), wof[1], ZERO, 0, 0, 0);
        floatx4 d2 = __builtin_amdgcn_mfma_f32_16x16x32_bf16(
                         *(const short8*)(ap + 64 + q * 8), wof[2], ZERO, 0, 0, 0);
        floatx4 d3 = __builtin_amdgcn_mfma_f32_16x16x32_bf16(
                         *(const short8*)(ap + 96 + q * 8), wof[3], ZERO, 0, 0, 0);
        floatx4 od = (d0 + d1) + (d2 + d3);
        if (l15 == 0) {
            floatx4 ov = {od[0] + bo, od[1] + bo, od[2] + bo, od[3] + bo};
            *(floatx4*)&out_lds[tp + q * 4] = ov;
        }
    }
    __syncthreads();
    out[b * T_ + tid] = out_lds[tid];
}

extern "C" void kernel_launch(void* const* d_in, const int* in_sizes, int n_in,
                              void* d_out, int out_size, void* d_ws, size_t ws_size,
                              hipStream_t stream) {
    const float* xd   = (const float*)d_in[0];
    const float* xs   = (const float*)d_in[1];
    const float* Wih  = (const float*)d_in[2];
    const float* Whh  = (const float*)d_in[3];
    const float* Wzh  = (const float*)d_in[4];
    const float* bias = (const float*)d_in[5];
    const float* Wout = (const float*)d_in[6];
    const float* bout = (const float*)d_in[7];
    float* o = (float*)d_out;
    hipLaunchKernelGGL(tamlstm_kernel, dim3(B_), dim3(512), 0, stream,
                       xd, xs, Wih, Whh, Wzh, bias, Wout, bout, o);
}